// Round 2
// baseline (238.250 us; speedup 1.0000x reference)
//
#include <hip/hip_runtime.h>
#include <stdint.h>
#include <math.h>

#define B_   4
#define L_   2048
#define H_   16
#define DH_  64
#define DM_  1024

typedef __bf16 bf16;
typedef __attribute__((ext_vector_type(8))) __bf16 bf16x8;
typedef __attribute__((ext_vector_type(4))) float f32x4;
typedef __attribute__((ext_vector_type(4))) int i32x4;
typedef __attribute__((ext_vector_type(4))) short s16x4;
typedef unsigned short u16;
typedef unsigned int u32;
typedef __attribute__((ext_vector_type(2))) unsigned int u32x2;
typedef __attribute__((ext_vector_type(4))) unsigned short u16x4;

typedef unsigned int u32g __attribute__((address_space(1)));
typedef unsigned int u32l __attribute__((address_space(3)));

__device__ __forceinline__ u16 f2bf(float f) {
  return __builtin_bit_cast(u16, (bf16)f);   // fptrunc = RNE
}

// 2^x via the HW transcendental unit (scores are kept in log2 units)
__device__ __forceinline__ float exp2_fast(float x) {
  float r; asm("v_exp_f32 %0, %1" : "=v"(r) : "v"(x)); return r;
}

// async global->LDS 16B; LDS dest must be wave-uniform base + lane*16
__device__ __forceinline__ void gload16(const void* g, void* l) {
  __builtin_amdgcn_global_load_lds((const u32g*)g, (u32l*)l, 16, 0, 0);
}

// K=16 bf16 MFMA: A/B are 4 bf16 per lane with k=(lane>>4)*4+j — this matches
// the C-layout of the QK 16x16x32 MFMA, so P needs NO cross-lane transpose.
__device__ __forceinline__ f32x4 mfma16(s16x4 a, s16x4 b, f32x4 c) {
#if __has_builtin(__builtin_amdgcn_mfma_f32_16x16x16bf16_1k)
  return __builtin_amdgcn_mfma_f32_16x16x16bf16_1k(a, b, c, 0, 0, 0);
#else
  asm volatile("v_mfma_f32_16x16x16_bf16 %0, %1, %2, %0\n\ts_nop 7\n\ts_nop 2"
               : "+v"(c) : "v"(a), "v"(b));
  return c;
#endif
}

// ---------------- f32 -> bf16 conversion ----------------
__global__ __launch_bounds__(256) void cvt_f32_bf16(const float* __restrict__ src,
                                                    u16* __restrict__ dst, int n4) {
  int i = blockIdx.x * 256 + threadIdx.x;
  if (i >= n4) return;
  f32x4 v = ((const f32x4*)src)[i];
  u16x4 o;
  o[0] = f2bf(v[0]); o[1] = f2bf(v[1]); o[2] = f2bf(v[2]); o[3] = f2bf(v[3]);
  ((u16x4*)dst)[i] = o;
}

// ---------------- per-key bias table: Bk[bh][l] (log2 units) ----------------
__global__ __launch_bounds__(256) void bias_fill(const float* __restrict__ ts,
                                                 const float* __restrict__ msk,
                                                 const float* __restrict__ decay,
                                                 float* __restrict__ Bk) {
  int i = blockIdx.x * 256 + threadIdx.x;        // 64*2048
  int bh = i >> 11, l = i & (L_ - 1);
  int b = bh >> 4, h = bh & 15;
  float dc24 = log1pf(__expf(decay[h])) * (1.0f / 24.0f) * 1.44269504f;
  float tv = ts[b * L_ + l], mv = msk[b * L_ + l];
  Bk[i] = (mv != 0.f) ? dc24 * tv : -INFINITY;
}

// ---------------- bf16 GEMM: C[m][n] = sum_k A[m][k]*Bm[n][k] + bias[n] ----------------
// mode 0: scatter into Qb (x 0.125*log2e!) / Kb ([bh][l][64]) and Vt ([bh][d][L]) as bf16
// mode 1: plain f32 out Cout
// 2-phase double-buffered staging: STAGE(next) issued BEFORE compute(current);
// ONE barrier per K-step. mode-0 transpose buffer ALIASES the staging LDS.
__global__ __launch_bounds__(256) void gemm_bf16(
    const u16* __restrict__ A, const u16* __restrict__ Bm, const float* __restrict__ bias,
    int M, int N, int K, int mode,
    u16* __restrict__ Qb, u16* __restrict__ Kb, u16* __restrict__ Vt, float* __restrict__ Cout)
{
  extern __shared__ char smem[];
  // staging: [0,8K)=lA0 [8K,16K)=lB0 [16K,24K)=lA1 [24K,32K)=lB1
  u16* ltr = (u16*)smem;            // mode0 epilogue alias: 128*136*2 = 34816B

  const int tid = threadIdx.x;
  const int m0 = blockIdx.y * 128, n0 = blockIdx.x * 128;
  const int lane = tid & 63, w = tid >> 6;
  const int g = lane >> 4, col = lane & 15;
  const int wr = w >> 1, wc = w & 1;

  f32x4 acc[4][4];
#pragma unroll
  for (int mt = 0; mt < 4; ++mt)
#pragma unroll
    for (int nt = 0; nt < 4; ++nt) {
      acc[mt][nt][0] = 0.f; acc[mt][nt][1] = 0.f;
      acc[mt][nt][2] = 0.f; acc[mt][nt][3] = 0.f;
    }

  auto STAGEG = [&](int k0, int nb) {
    char* dA = smem + (nb << 14);
    char* dB = dA + 8192;
#pragma unroll
    for (int hh = 0; hh < 2; ++hh) {
      int c = tid + hh * 256;
      int row = c >> 2, sub = c & 3;
      int sc = sub ^ ((row >> 1) & 3);
      gload16(A  + (size_t)(m0 + row) * K + (k0 + sc * 8), dA + c * 16);
      gload16(Bm + (size_t)(n0 + row) * K + (k0 + sc * 8), dB + c * 16);
    }
  };

  STAGEG(0, 0);
  __syncthreads();

  const int nk = K >> 5;
  for (int i = 0; i < nk; ++i) {
    const int cur = i & 1;
    if (i + 1 < nk) STAGEG((i + 1) * 32, cur ^ 1);   // async prefetch over compute

    const char* bufA = smem + (cur << 14);
    const char* bufB = bufA + 8192;
    bf16x8 af[4], bfr[4];
#pragma unroll
    for (int mt = 0; mt < 4; ++mt) {
      int row = wr * 64 + mt * 16 + col;
      af[mt] = *(const bf16x8*)(bufA + row * 64 + ((g ^ ((row >> 1) & 3)) << 4));
    }
#pragma unroll
    for (int nt = 0; nt < 4; ++nt) {
      int row = wc * 64 + nt * 16 + col;
      bfr[nt] = *(const bf16x8*)(bufB + row * 64 + ((g ^ ((row >> 1) & 3)) << 4));
    }
#pragma unroll
    for (int mt = 0; mt < 4; ++mt)
#pragma unroll
      for (int nt = 0; nt < 4; ++nt)
        acc[mt][nt] = __builtin_amdgcn_mfma_f32_16x16x32_bf16(af[mt], bfr[nt], acc[mt][nt], 0, 0, 0);

    __syncthreads();   // drains vmcnt(0): next buffer complete; current reusable
  }

  if (mode == 1) {
#pragma unroll
    for (int nt = 0; nt < 4; ++nt) {
      int gn = n0 + wc * 64 + nt * 16 + col;
      float bv = bias[gn];
#pragma unroll
      for (int mt = 0; mt < 4; ++mt) {
        int mbase = m0 + wr * 64 + mt * 16 + g * 4;
#pragma unroll
        for (int r = 0; r < 4; ++r)
          Cout[(size_t)(mbase + r) * N + gn] = acc[mt][nt][r] + bv;
      }
    }
    return;
  }

  // mode 0 epilogue via padded LDS transpose (stride 136 u16), aliasing staging
  const int type = n0 >> 10;               // 0=q 1=k 2=v
  // fold dh^-0.5 AND log2(e) into Q (softmax runs in log2 units)
  const float qsc = (type == 0) ? 0.125f * 1.44269504f : 1.0f;
#pragma unroll
  for (int nt = 0; nt < 4; ++nt) {
    int nn = wc * 64 + nt * 16 + col;
    float bv = bias[n0 + nn];
#pragma unroll
    for (int mt = 0; mt < 4; ++mt) {
      int mm = wr * 64 + mt * 16 + g * 4;
#pragma unroll
      for (int r = 0; r < 4; ++r) {
        u16 hv = f2bf((acc[mt][nt][r] + bv) * qsc);
        if (type < 2) ltr[(mm + r) * 136 + nn] = hv;
        else          ltr[nn * 136 + (mm + r)] = hv;
      }
    }
  }
  __syncthreads();
#pragma unroll
  for (int it = 0; it < 8; ++it) {
    int cid = tid + it * 256;
    int rrow = cid >> 4, cc = cid & 15;
    i32x4 v = *(const i32x4*)((const char*)ltr + rrow * 272 + cc * 16);
    if (type < 2) {
      int token = m0 + rrow;
      int bb = token >> 11, ll = token & (L_ - 1);
      int gn = n0 + cc * 8;
      int head = (gn & 1023) >> 6, d = gn & 63;
      u16* dst = (type == 0) ? Qb : Kb;
      *(i32x4*)(dst + ((size_t)((bb * H_ + head) * L_ + ll)) * 64 + d) = v;
    } else {
      int gn = n0 + rrow;
      int head = (gn & 1023) >> 6, d = gn & 63;
      int token0 = m0 + cc * 8;
      int bb = token0 >> 11, ll = token0 & (L_ - 1);
      *(i32x4*)(Vt + ((size_t)((bb * H_ + head) * DH_ + d)) * L_ + ll) = v;
    }
  }
}

// ---------------- fused temporal flash attention ----------------
// R11 = R10 minus register spill:
//  * __launch_bounds__(512, 2): measured behavior of the 2nd arg is CUDA-style
//    min-blocks/CU -> (512,4) capped VGPRs at 64 and spilled ~13MB to scratch
//    (WRITE_SIZE 16.4->29.7MB). (512,2) -> 2 blocks/CU, 128-reg cap.
//  * SINGLE state set (o[4], qf[2], m, l): tile A's output is written out
//    mid-loop at the A->B switch via a DIRECT global epilogue (no LDS
//    transpose buffer, no extra barriers), so A and B state never coexist.
//    Saves ~24 VGPRs -> fits the 128 cap with room.
//  * LDS bank "conflicts" on the K b128 / V b64 reads are at the 128B/clk
//    LDS BW floor (8x16B resp. 4x8B per bank-group) — counted, but optimal.
__global__ __launch_bounds__(512, 2) void attn_fwd(
    const u16* __restrict__ Qb, const u16* __restrict__ Kb, const u16* __restrict__ Vt,
    const float* __restrict__ Bk, u16* __restrict__ AO)
{
  __shared__ u16 lK[2][64 * 64];     // [key][dh] swz ^(key&7)   16KB
  __shared__ u16 lV[2][64 * 64];     // [d][key]  swz ^(d&7)     16KB

  const int phys = blockIdx.x;            // 512 blocks
  const int xcd = phys & 7, s = phys >> 3;
  const int bh = xcd * 8 + (s >> 3);
  const int pr = s & 7;
  const int qa = pr, qbt = 15 - pr;       // the two 128-row q-tiles of this block
  const int b = bh >> 4, h = bh & 15;

  const int tid = threadIdx.x, w = tid >> 6, lane = tid & 63;
  const int g = lane >> 4, q16 = lane & 15;

  const float* Bkb = Bk + (size_t)bh * L_;

  // mutable per-tile state, REUSED across the A->B switch
  int qrow = qa * 128 + w * 16;           // wave's 16-row slice
  int mkt  = (qrow + 79) >> 6;            // causal tile bound
  bf16x8 qf[2];
  {
    const u16* Qr = Qb + ((size_t)bh * L_ + qrow + q16) * 64;
    qf[0] = *(const bf16x8*)(Qr + g * 8);
    qf[1] = *(const bf16x8*)(Qr + 32 + g * 8);
  }
  float m_r = -INFINITY, l_r = 0.f;
  f32x4 o[4];
#pragma unroll
  for (int db = 0; db < 4; ++db) {
    o[db][0] = 0.f; o[db][1] = 0.f; o[db][2] = 0.f; o[db][3] = 0.f;
  }

  // per-lane LDS column offsets (swizzle-resolved once)
  int kcol[2], vcol[4];
#pragma unroll
  for (int kk = 0; kk < 2; ++kk) kcol[kk] = ((kk * 4 + g) ^ (q16 & 7)) << 4;
#pragma unroll
  for (int t = 0; t < 4; ++t)
    vcol[t] = (((2 * t + (g >> 1)) ^ (q16 & 7)) << 4) + (g & 1) * 8;

  const int nkA = (qa + 1) * 2;
  const int ns  = 34;                     // (qa+1)*2 + (qbt+1)*2, uniform

  auto STAGE = [&](int kt, int nb) {
    const int kg0 = kt * 64;
    const int r8 = tid >> 3, cc = tid & 7;   // 512 threads: 64 rows x 8 granules
    gload16(Kb + ((size_t)bh * L_ + kg0 + r8) * 64 + ((cc ^ (r8 & 7)) * 8),
            (char*)lK[nb] + tid * 16);
    gload16(Vt + ((size_t)(bh * 64 + r8)) * L_ + kg0 + ((cc ^ (r8 & 7)) * 8),
            (char*)lV[nb] + tid * 16);
  };

  auto BODY = [&](int kg0, int cur) {
    // per-key bias (L2-hot; latency hides under the QK MFMAs)
    f32x4 bk[4];
#pragma unroll
    for (int t = 0; t < 4; ++t)
      bk[t] = *(const f32x4*)(Bkb + kg0 + t * 16 + g * 4);

    // ---- S^T = K · Q^T ----
    f32x4 sv[4];
#pragma unroll
    for (int t = 0; t < 4; ++t) { sv[t][0] = 0.f; sv[t][1] = 0.f; sv[t][2] = 0.f; sv[t][3] = 0.f; }
    __builtin_amdgcn_s_setprio(1);
#pragma unroll
    for (int t = 0; t < 4; ++t) {
      const char* krow = (const char*)lK[cur] + t * 2048 + q16 * 128;
#pragma unroll
      for (int kk = 0; kk < 2; ++kk) {
        bf16x8 kf = *(const bf16x8*)(krow + kcol[kk]);
        sv[t] = __builtin_amdgcn_mfma_f32_16x16x32_bf16(kf, qf[kk], sv[t], 0, 0, 0);
      }
    }
    __builtin_amdgcn_s_setprio(0);

    // ---- add per-key bias (log2 units) ----
#pragma unroll
    for (int t = 0; t < 4; ++t) {
      sv[t][0] += bk[t][0]; sv[t][1] += bk[t][1];
      sv[t][2] += bk[t][2]; sv[t][3] += bk[t][3];
    }

    // ---- causal mask (diagonal tiles only; wave-uniform branch) ----
    if (kg0 + 63 > qrow) {
      const int qg = qrow + q16;
#pragma unroll
      for (int t = 0; t < 4; ++t)
#pragma unroll
        for (int r = 0; r < 4; ++r)
          sv[t][r] = (kg0 + t * 16 + g * 4 + r <= qg) ? sv[t][r] : -INFINITY;
    }

    // ---- online softmax (log2 units, defer-rescale THR=8) ----
    float mx = sv[0][0];
#pragma unroll
    for (int t = 0; t < 4; ++t)
#pragma unroll
      for (int r = 0; r < 4; ++r) mx = fmaxf(mx, sv[t][r]);
    mx = fmaxf(mx, __shfl_xor(mx, 16));
    mx = fmaxf(mx, __shfl_xor(mx, 32));

    float mn = m_r;
    if (__any(mx > m_r + 8.f)) {
      mn = fmaxf(m_r, mx);
      float al = exp2_fast(m_r - mn);
      m_r = mn;
      l_r *= al;
#pragma unroll
      for (int db = 0; db < 4; ++db) {
        o[db][0] *= al; o[db][1] *= al; o[db][2] *= al; o[db][3] *= al;
      }
    }
    float rs = 0.f;
#pragma unroll
    for (int t = 0; t < 4; ++t)
#pragma unroll
      for (int r = 0; r < 4; ++r) {
        float pv = exp2_fast(sv[t][r] - mn);
        sv[t][r] = pv;
        rs += pv;
      }
    rs += __shfl_xor(rs, 16);
    rs += __shfl_xor(rs, 32);
    l_r += rs;

    // ---- pack P in-register: QK C-layout == K=16 B-fragment layout ----
    s16x4 pf[4];
#pragma unroll
    for (int t = 0; t < 4; ++t) {
      s16x4 pp;
      pp[0] = (short)f2bf(sv[t][0]); pp[1] = (short)f2bf(sv[t][1]);
      pp[2] = (short)f2bf(sv[t][2]); pp[3] = (short)f2bf(sv[t][3]);
      pf[t] = pp;
    }

    // ---- PV: O^T += V^T · P  (16 x mfma 16x16x16, V as b64 A-fragments) ----
    __builtin_amdgcn_s_setprio(1);
#pragma unroll
    for (int t = 0; t < 4; ++t) {
      const char* vrow = (const char*)lV[cur] + q16 * 128 + vcol[t];
#pragma unroll
      for (int db = 0; db < 4; ++db) {
        s16x4 vf = *(const s16x4*)(vrow + db * 2048);
        o[db] = mfma16(vf, pf[t], o[db]);
      }
    }
    __builtin_amdgcn_s_setprio(0);
  };

  // direct global epilogue: lane q16 owns O^T column q -> its row of AO is
  // contiguous in d; the wave's 4 db-stores fully cover each 128B head-chunk
  // so L2 write-combines to full lines.
  auto EPI = [&](int qt) {
    float inv = 1.f / l_r;
    u16* dst = AO + ((size_t)(b * L_ + qt * 128 + w * 16 + q16)) * DM_ + h * 64 + g * 4;
#pragma unroll
    for (int db = 0; db < 4; ++db) {
      u32x2 pk;
      pk[0] = (u32)f2bf(o[db][0] * inv) | ((u32)f2bf(o[db][1] * inv) << 16);
      pk[1] = (u32)f2bf(o[db][2] * inv) | ((u32)f2bf(o[db][3] * inv) << 16);
      *(u32x2*)(dst + db * 16) = pk;
    }
  };

  STAGE(0, 0);
  __syncthreads();

  for (int st = 0; st < ns; ++st) {
    const int cur = st & 1;
    if (st + 1 < ns) {
      const int nst = st + 1;
      STAGE(nst < nkA ? nst : nst - nkA, cur ^ 1);   // async prefetch over compute
    }
    if (st < nkA) {
      if (st < mkt) BODY(st * 64, cur);
    } else {
      if (st == nkA) {
        // ---- A -> B switch: issue B's Q loads, drain A, reset state ----
        qrow = qbt * 128 + w * 16;
        const u16* Qr = Qb + ((size_t)bh * L_ + qrow + q16) * 64;
        bf16x8 nq0 = *(const bf16x8*)(Qr + g * 8);
        bf16x8 nq1 = *(const bf16x8*)(Qr + 32 + g * 8);
        EPI(qa);
        qf[0] = nq0; qf[1] = nq1;
        mkt = (qrow + 79) >> 6;
        m_r = -INFINITY; l_r = 0.f;
#pragma unroll
        for (int db = 0; db < 4; ++db) {
          o[db][0] = 0.f; o[db][1] = 0.f; o[db][2] = 0.f; o[db][3] = 0.f;
        }
      }
      const int kt = st - nkA;
      if (kt < mkt) BODY(kt * 64, cur);
    }
    __syncthreads();   // drains vmcnt(0): next buffer complete; current reusable
  }
  EPI(qbt);
}

// ---------------- launcher ----------------
extern "C" void kernel_launch(void* const* d_in, const int* in_sizes, int n_in,
                              void* d_out, int out_size, void* d_ws, size_t ws_size,
                              hipStream_t stream) {
  const float* x    = (const float*)d_in[0];
  const float* ts   = (const float*)d_in[1];
  const float* mk   = (const float*)d_in[2];
  const float* Wqkv = (const float*)d_in[3];
  const float* bqkv = (const float*)d_in[4];
  const float* Wout = (const float*)d_in[5];
  const float* bout = (const float*)d_in[6];
  const float* dec  = (const float*)d_in[7];
  float* out = (float*)d_out;

  char* ws = (char*)d_ws;
  u16* xbf  = (u16*)(ws + 0);
  u16* wqbf = (u16*)(ws + 16777216);
  u16* wobf = (u16*)(ws + 23068672);
  u16* Qb   = (u16*)(ws + 25165824);
  u16* Kb   = (u16*)(ws + 41943040);
  u16* Vt   = (u16*)(ws + 58720256);
  u16* AO   = (u16*)(ws + 75497472);
  float* Bk = (float*)(ws + 92274688);   // 64*2048*4 = 512KB

  cvt_f32_bf16<<<dim3(8192 * 1024 / 4 / 256), 256, 0, stream>>>(x, xbf, 8192 * 1024 / 4);
  cvt_f32_bf16<<<dim3(3072 * 1024 / 4 / 256), 256, 0, stream>>>(Wqkv, wqbf, 3072 * 1024 / 4);
  cvt_f32_bf16<<<dim3(1024 * 1024 / 4 / 256), 256, 0, stream>>>(Wout, wobf, 1024 * 1024 / 4);

  bias_fill<<<dim3(64 * 2048 / 256), 256, 0, stream>>>(ts, mk, dec, Bk);

  gemm_bf16<<<dim3(3072 / 128, 8192 / 128), 256, 34816, stream>>>(
      xbf, wqbf, bqkv, 8192, 3072, 1024, 0, Qb, Kb, Vt, nullptr);

  attn_fwd<<<dim3(512), 512, 0, stream>>>(Qb, Kb, Vt, Bk, AO);

  gemm_bf16<<<dim3(1024 / 128, 8192 / 128), 256, 32768, stream>>>(
      AO, wobf, bout, 8192, 1024, 1024, 1, nullptr, nullptr, nullptr, out);
}

// Round 3
// 196.844 us; speedup vs baseline: 1.2103x; 1.2103x over previous
//
#include <hip/hip_runtime.h>
#include <stdint.h>
#include <math.h>

#define B_   4
#define L_   2048
#define H_   16
#define DH_  64
#define DM_  1024

typedef __bf16 bf16;
typedef __attribute__((ext_vector_type(8))) __bf16 bf16x8;
typedef __attribute__((ext_vector_type(4))) float f32x4;
typedef __attribute__((ext_vector_type(4))) int i32x4;
typedef __attribute__((ext_vector_type(4))) short s16x4;
typedef unsigned short u16;
typedef unsigned int u32;
typedef __attribute__((ext_vector_type(2))) unsigned int u32x2;
typedef __attribute__((ext_vector_type(4))) unsigned short u16x4;

typedef unsigned int u32g __attribute__((address_space(1)));
typedef unsigned int u32l __attribute__((address_space(3)));

__device__ __forceinline__ u16 f2bf(float f) {
  return __builtin_bit_cast(u16, (bf16)f);   // fptrunc = RNE
}

// 2^x via the HW transcendental unit (scores are kept in log2 units)
__device__ __forceinline__ float exp2_fast(float x) {
  float r; asm("v_exp_f32 %0, %1" : "=v"(r) : "v"(x)); return r;
}

// async global->LDS 16B; LDS dest must be wave-uniform base + lane*16
__device__ __forceinline__ void gload16(const void* g, void* l) {
  __builtin_amdgcn_global_load_lds((const u32g*)g, (u32l*)l, 16, 0, 0);
}

// K=16 bf16 MFMA: A/B are 4 bf16 per lane with k=(lane>>4)*4+j — this matches
// the C-layout of the QK 16x16x32 MFMA, so P needs NO cross-lane transpose.
__device__ __forceinline__ f32x4 mfma16(s16x4 a, s16x4 b, f32x4 c) {
#if __has_builtin(__builtin_amdgcn_mfma_f32_16x16x16bf16_1k)
  return __builtin_amdgcn_mfma_f32_16x16x16bf16_1k(a, b, c, 0, 0, 0);
#else
  asm volatile("v_mfma_f32_16x16x16_bf16 %0, %1, %2, %0\n\ts_nop 7\n\ts_nop 2"
               : "+v"(c) : "v"(a), "v"(b));
  return c;
#endif
}

// ---------------- f32 -> bf16 conversion ----------------
__global__ __launch_bounds__(256) void cvt_f32_bf16(const float* __restrict__ src,
                                                    u16* __restrict__ dst, int n4) {
  int i = blockIdx.x * 256 + threadIdx.x;
  if (i >= n4) return;
  f32x4 v = ((const f32x4*)src)[i];
  u16x4 o;
  o[0] = f2bf(v[0]); o[1] = f2bf(v[1]); o[2] = f2bf(v[2]); o[3] = f2bf(v[3]);
  ((u16x4*)dst)[i] = o;
}

// ---------------- per-key bias table: Bk[bh][l] (log2 units) ----------------
__global__ __launch_bounds__(256) void bias_fill(const float* __restrict__ ts,
                                                 const float* __restrict__ msk,
                                                 const float* __restrict__ decay,
                                                 float* __restrict__ Bk) {
  int i = blockIdx.x * 256 + threadIdx.x;        // 64*2048
  int bh = i >> 11, l = i & (L_ - 1);
  int b = bh >> 4, h = bh & 15;
  float dc24 = log1pf(__expf(decay[h])) * (1.0f / 24.0f) * 1.44269504f;
  float tv = ts[b * L_ + l], mv = msk[b * L_ + l];
  Bk[i] = (mv != 0.f) ? dc24 * tv : -INFINITY;
}

// ---------------- bf16 GEMM: C[m][n] = sum_k A[m][k]*Bm[n][k] + bias[n] ----------------
// mode 0: scatter into Qb (x 0.125*log2e!) / Kb ([bh][l][64]) and Vt ([bh][d][L]) as bf16
// mode 1: plain f32 out Cout
// 2-phase double-buffered staging: STAGE(next) issued BEFORE compute(current);
// ONE barrier per K-step. mode-0 transpose buffer ALIASES the staging LDS.
__global__ __launch_bounds__(256) void gemm_bf16(
    const u16* __restrict__ A, const u16* __restrict__ Bm, const float* __restrict__ bias,
    int M, int N, int K, int mode,
    u16* __restrict__ Qb, u16* __restrict__ Kb, u16* __restrict__ Vt, float* __restrict__ Cout)
{
  extern __shared__ char smem[];
  // staging: [0,8K)=lA0 [8K,16K)=lB0 [16K,24K)=lA1 [24K,32K)=lB1
  u16* ltr = (u16*)smem;            // mode0 epilogue alias: 128*136*2 = 34816B

  const int tid = threadIdx.x;
  const int m0 = blockIdx.y * 128, n0 = blockIdx.x * 128;
  const int lane = tid & 63, w = tid >> 6;
  const int g = lane >> 4, col = lane & 15;
  const int wr = w >> 1, wc = w & 1;

  f32x4 acc[4][4];
#pragma unroll
  for (int mt = 0; mt < 4; ++mt)
#pragma unroll
    for (int nt = 0; nt < 4; ++nt) {
      acc[mt][nt][0] = 0.f; acc[mt][nt][1] = 0.f;
      acc[mt][nt][2] = 0.f; acc[mt][nt][3] = 0.f;
    }

  auto STAGEG = [&](int k0, int nb) {
    char* dA = smem + (nb << 14);
    char* dB = dA + 8192;
#pragma unroll
    for (int hh = 0; hh < 2; ++hh) {
      int c = tid + hh * 256;
      int row = c >> 2, sub = c & 3;
      int sc = sub ^ ((row >> 1) & 3);
      gload16(A  + (size_t)(m0 + row) * K + (k0 + sc * 8), dA + c * 16);
      gload16(Bm + (size_t)(n0 + row) * K + (k0 + sc * 8), dB + c * 16);
    }
  };

  STAGEG(0, 0);
  __syncthreads();

  const int nk = K >> 5;
  for (int i = 0; i < nk; ++i) {
    const int cur = i & 1;
    if (i + 1 < nk) STAGEG((i + 1) * 32, cur ^ 1);   // async prefetch over compute

    const char* bufA = smem + (cur << 14);
    const char* bufB = bufA + 8192;
    bf16x8 af[4], bfr[4];
#pragma unroll
    for (int mt = 0; mt < 4; ++mt) {
      int row = wr * 64 + mt * 16 + col;
      af[mt] = *(const bf16x8*)(bufA + row * 64 + ((g ^ ((row >> 1) & 3)) << 4));
    }
#pragma unroll
    for (int nt = 0; nt < 4; ++nt) {
      int row = wc * 64 + nt * 16 + col;
      bfr[nt] = *(const bf16x8*)(bufB + row * 64 + ((g ^ ((row >> 1) & 3)) << 4));
    }
#pragma unroll
    for (int mt = 0; mt < 4; ++mt)
#pragma unroll
      for (int nt = 0; nt < 4; ++nt)
        acc[mt][nt] = __builtin_amdgcn_mfma_f32_16x16x32_bf16(af[mt], bfr[nt], acc[mt][nt], 0, 0, 0);

    __syncthreads();   // drains vmcnt(0): next buffer complete; current reusable
  }

  if (mode == 1) {
#pragma unroll
    for (int nt = 0; nt < 4; ++nt) {
      int gn = n0 + wc * 64 + nt * 16 + col;
      float bv = bias[gn];
#pragma unroll
      for (int mt = 0; mt < 4; ++mt) {
        int mbase = m0 + wr * 64 + mt * 16 + g * 4;
#pragma unroll
        for (int r = 0; r < 4; ++r)
          Cout[(size_t)(mbase + r) * N + gn] = acc[mt][nt][r] + bv;
      }
    }
    return;
  }

  // mode 0 epilogue via padded LDS transpose (stride 136 u16), aliasing staging
  const int type = n0 >> 10;               // 0=q 1=k 2=v
  // fold dh^-0.5 AND log2(e) into Q (softmax runs in log2 units)
  const float qsc = (type == 0) ? 0.125f * 1.44269504f : 1.0f;
#pragma unroll
  for (int nt = 0; nt < 4; ++nt) {
    int nn = wc * 64 + nt * 16 + col;
    float bv = bias[n0 + nn];
#pragma unroll
    for (int mt = 0; mt < 4; ++mt) {
      int mm = wr * 64 + mt * 16 + g * 4;
#pragma unroll
      for (int r = 0; r < 4; ++r) {
        u16 hv = f2bf((acc[mt][nt][r] + bv) * qsc);
        if (type < 2) ltr[(mm + r) * 136 + nn] = hv;
        else          ltr[nn * 136 + (mm + r)] = hv;
      }
    }
  }
  __syncthreads();
#pragma unroll
  for (int it = 0; it < 8; ++it) {
    int cid = tid + it * 256;
    int rrow = cid >> 4, cc = cid & 15;
    i32x4 v = *(const i32x4*)((const char*)ltr + rrow * 272 + cc * 16);
    if (type < 2) {
      int token = m0 + rrow;
      int bb = token >> 11, ll = token & (L_ - 1);
      int gn = n0 + cc * 8;
      int head = (gn & 1023) >> 6, d = gn & 63;
      u16* dst = (type == 0) ? Qb : Kb;
      *(i32x4*)(dst + ((size_t)((bb * H_ + head) * L_ + ll)) * 64 + d) = v;
    } else {
      int gn = n0 + rrow;
      int head = (gn & 1023) >> 6, d = gn & 63;
      int token0 = m0 + cc * 8;
      int bb = token0 >> 11, ll = token0 & (L_ - 1);
      *(i32x4*)(Vt + ((size_t)((bb * H_ + head) * DH_ + d)) * L_ + ll) = v;
    }
  }
}

// ---------------- fused temporal flash attention ----------------
// R12: two explicit per-tile loops (A then B), loop-local state.
//  * R11's merged mutable state (qrow/mkt/qf/o reset mid-loop) blocked the
//    loop split the compiler did for R10 -> worse schedule, 132us. Here the
//    split is in SOURCE: each loop has freshly-scoped state (no cold spill:
//    B's state is born after A's dies), tight bodies, const-per-loop bounds.
//  * Shared staging pipeline across the seam: loop A's last iteration
//    prefetches B's k-tile 0; nkA is even so buffer parity carries over.
//  * Deferred l-reduction: per-lane partial l_r (rescale al is row-uniform),
//    cross-lane sum ONCE in the epilogue -> 2 fewer ds_permute per step.
//  * Direct global epilogue (no LDS transpose, no barriers).
__global__ __launch_bounds__(512, 2) void attn_fwd(
    const u16* __restrict__ Qb, const u16* __restrict__ Kb, const u16* __restrict__ Vt,
    const float* __restrict__ Bk, u16* __restrict__ AO)
{
  __shared__ u16 lK[2][64 * 64];     // [key][dh] swz ^(key&7)   16KB
  __shared__ u16 lV[2][64 * 64];     // [d][key]  swz ^(d&7)     16KB

  const int phys = blockIdx.x;            // 512 blocks
  const int xcd = phys & 7, s = phys >> 3;
  const int bh = xcd * 8 + (s >> 3);
  const int pr = s & 7;
  const int qa = pr, qbt = 15 - pr;       // the two 128-row q-tiles of this block
  const int b = bh >> 4, h = bh & 15;

  const int tid = threadIdx.x, w = tid >> 6, lane = tid & 63;
  const int g = lane >> 4, q16 = lane & 15;

  const float* Bkb = Bk + (size_t)bh * L_;

  // per-lane LDS column offsets (swizzle-resolved once)
  int kcol[2], vcol[4];
#pragma unroll
  for (int kk = 0; kk < 2; ++kk) kcol[kk] = ((kk * 4 + g) ^ (q16 & 7)) << 4;
#pragma unroll
  for (int t = 0; t < 4; ++t)
    vcol[t] = (((2 * t + (g >> 1)) ^ (q16 & 7)) << 4) + (g & 1) * 8;

  const int nkA = (qa + 1) * 2;           // even
  const int nkB = (qbt + 1) * 2;

  auto STAGE = [&](int kt, int nb) {
    const int kg0 = kt * 64;
    const int r8 = tid >> 3, cc = tid & 7;   // 512 threads: 64 rows x 8 granules
    gload16(Kb + ((size_t)bh * L_ + kg0 + r8) * 64 + ((cc ^ (r8 & 7)) * 8),
            (char*)lK[nb] + tid * 16);
    gload16(Vt + ((size_t)(bh * 64 + r8)) * L_ + kg0 + ((cc ^ (r8 & 7)) * 8),
            (char*)lV[nb] + tid * 16);
  };

  auto BODY = [&](bf16x8 (&qf)[2], f32x4 (&o)[4], float& m_r, float& l_r,
                  int qrow, int kg0, int cur) {
    // per-key bias (L2-hot; latency hides under the QK MFMAs)
    f32x4 bk[4];
#pragma unroll
    for (int t = 0; t < 4; ++t)
      bk[t] = *(const f32x4*)(Bkb + kg0 + t * 16 + g * 4);

    // ---- S^T = K · Q^T ----
    f32x4 sv[4];
#pragma unroll
    for (int t = 0; t < 4; ++t) { sv[t][0] = 0.f; sv[t][1] = 0.f; sv[t][2] = 0.f; sv[t][3] = 0.f; }
    __builtin_amdgcn_s_setprio(1);
#pragma unroll
    for (int t = 0; t < 4; ++t) {
      const char* krow = (const char*)lK[cur] + t * 2048 + q16 * 128;
#pragma unroll
      for (int kk = 0; kk < 2; ++kk) {
        bf16x8 kf = *(const bf16x8*)(krow + kcol[kk]);
        sv[t] = __builtin_amdgcn_mfma_f32_16x16x32_bf16(kf, qf[kk], sv[t], 0, 0, 0);
      }
    }
    __builtin_amdgcn_s_setprio(0);

    // ---- add per-key bias (log2 units) ----
#pragma unroll
    for (int t = 0; t < 4; ++t) {
      sv[t][0] += bk[t][0]; sv[t][1] += bk[t][1];
      sv[t][2] += bk[t][2]; sv[t][3] += bk[t][3];
    }

    // ---- causal mask (diagonal tiles only; wave-uniform branch) ----
    if (kg0 + 63 > qrow) {
      const int qg = qrow + q16;
#pragma unroll
      for (int t = 0; t < 4; ++t)
#pragma unroll
        for (int r = 0; r < 4; ++r)
          sv[t][r] = (kg0 + t * 16 + g * 4 + r <= qg) ? sv[t][r] : -INFINITY;
    }

    // ---- online softmax (log2 units, defer-rescale THR=8) ----
    float mx = sv[0][0];
#pragma unroll
    for (int t = 0; t < 4; ++t)
#pragma unroll
      for (int r = 0; r < 4; ++r) mx = fmaxf(mx, sv[t][r]);
    mx = fmaxf(mx, __shfl_xor(mx, 16));
    mx = fmaxf(mx, __shfl_xor(mx, 32));

    float mn = m_r;
    if (__any(mx > m_r + 8.f)) {
      mn = fmaxf(m_r, mx);
      float al = exp2_fast(m_r - mn);
      m_r = mn;
      l_r *= al;
#pragma unroll
      for (int db = 0; db < 4; ++db) {
        o[db][0] *= al; o[db][1] *= al; o[db][2] *= al; o[db][3] *= al;
      }
    }
    float rs = 0.f;
#pragma unroll
    for (int t = 0; t < 4; ++t)
#pragma unroll
      for (int r = 0; r < 4; ++r) {
        float pv = exp2_fast(sv[t][r] - mn);
        sv[t][r] = pv;
        rs += pv;
      }
    l_r += rs;   // per-lane partial; cross-lane reduce deferred to epilogue

    // ---- pack P in-register: QK C-layout == K=16 B-fragment layout ----
    s16x4 pf[4];
#pragma unroll
    for (int t = 0; t < 4; ++t) {
      s16x4 pp;
      pp[0] = (short)f2bf(sv[t][0]); pp[1] = (short)f2bf(sv[t][1]);
      pp[2] = (short)f2bf(sv[t][2]); pp[3] = (short)f2bf(sv[t][3]);
      pf[t] = pp;
    }

    // ---- PV: O^T += V^T · P  (16 x mfma 16x16x16, V as b64 A-fragments) ----
    __builtin_amdgcn_s_setprio(1);
#pragma unroll
    for (int t = 0; t < 4; ++t) {
      const char* vrow = (const char*)lV[cur] + q16 * 128 + vcol[t];
#pragma unroll
      for (int db = 0; db < 4; ++db) {
        s16x4 vf = *(const s16x4*)(vrow + db * 2048);
        o[db] = mfma16(vf, pf[t], o[db]);
      }
    }
    __builtin_amdgcn_s_setprio(0);
  };

  // direct global epilogue: lane q16 owns O^T column q; wave's stores fully
  // cover each 128B head-chunk so L2 write-combines to full lines.
  auto EPI = [&](f32x4 (&o)[4], float l_r, int qt) {
    float lt = l_r + __shfl_xor(l_r, 16);
    lt += __shfl_xor(lt, 32);
    float inv = 1.f / lt;
    u16* dst = AO + ((size_t)(b * L_ + qt * 128 + w * 16 + q16)) * DM_ + h * 64 + g * 4;
#pragma unroll
    for (int db = 0; db < 4; ++db) {
      u32x2 pk;
      pk[0] = (u32)f2bf(o[db][0] * inv) | ((u32)f2bf(o[db][1] * inv) << 16);
      pk[1] = (u32)f2bf(o[db][2] * inv) | ((u32)f2bf(o[db][3] * inv) << 16);
      *(u32x2*)(dst + db * 16) = pk;
    }
  };

  STAGE(0, 0);
  __syncthreads();

  // ================= tile A =================
  {
    const int qrow = qa * 128 + w * 16;
    const int mkt = (qrow + 79) >> 6;
    bf16x8 qf[2];
    {
      const u16* Qr = Qb + ((size_t)bh * L_ + qrow + q16) * 64;
      qf[0] = *(const bf16x8*)(Qr + g * 8);
      qf[1] = *(const bf16x8*)(Qr + 32 + g * 8);
    }
    float m_r = -INFINITY, l_r = 0.f;
    f32x4 o[4];
#pragma unroll
    for (int db = 0; db < 4; ++db) {
      o[db][0] = 0.f; o[db][1] = 0.f; o[db][2] = 0.f; o[db][3] = 0.f;
    }
    for (int st = 0; st < nkA; ++st) {
      const int cur = st & 1;
      if (st + 1 < nkA) STAGE(st + 1, cur ^ 1);
      else              STAGE(0, cur ^ 1);        // prefetch B's k-tile 0
      if (st < mkt) BODY(qf, o, m_r, l_r, qrow, st * 64, cur);
      __syncthreads();   // drains vmcnt(0): next buffer complete; current reusable
    }
    EPI(o, l_r, qa);
  }

  // ================= tile B =================
  {
    const int qrow = qbt * 128 + w * 16;
    const int mkt = (qrow + 79) >> 6;
    bf16x8 qf[2];
    {
      const u16* Qr = Qb + ((size_t)bh * L_ + qrow + q16) * 64;
      qf[0] = *(const bf16x8*)(Qr + g * 8);
      qf[1] = *(const bf16x8*)(Qr + 32 + g * 8);
    }
    float m_r = -INFINITY, l_r = 0.f;
    f32x4 o[4];
#pragma unroll
    for (int db = 0; db < 4; ++db) {
      o[db][0] = 0.f; o[db][1] = 0.f; o[db][2] = 0.f; o[db][3] = 0.f;
    }
    for (int kt = 0; kt < nkB; ++kt) {
      const int cur = kt & 1;                     // nkA even -> parity continues
      if (kt + 1 < nkB) STAGE(kt + 1, cur ^ 1);
      if (kt < mkt) BODY(qf, o, m_r, l_r, qrow, kt * 64, cur);
      __syncthreads();
    }
    EPI(o, l_r, qbt);
  }
}

// ---------------- launcher ----------------
extern "C" void kernel_launch(void* const* d_in, const int* in_sizes, int n_in,
                              void* d_out, int out_size, void* d_ws, size_t ws_size,
                              hipStream_t stream) {
  const float* x    = (const float*)d_in[0];
  const float* ts   = (const float*)d_in[1];
  const float* mk   = (const float*)d_in[2];
  const float* Wqkv = (const float*)d_in[3];
  const float* bqkv = (const float*)d_in[4];
  const float* Wout = (const float*)d_in[5];
  const float* bout = (const float*)d_in[6];
  const float* dec  = (const float*)d_in[7];
  float* out = (float*)d_out;

  char* ws = (char*)d_ws;
  u16* xbf  = (u16*)(ws + 0);
  u16* wqbf = (u16*)(ws + 16777216);
  u16* wobf = (u16*)(ws + 23068672);
  u16* Qb   = (u16*)(ws + 25165824);
  u16* Kb   = (u16*)(ws + 41943040);
  u16* Vt   = (u16*)(ws + 58720256);
  u16* AO   = (u16*)(ws + 75497472);
  float* Bk = (float*)(ws + 92274688);   // 64*2048*4 = 512KB

  cvt_f32_bf16<<<dim3(8192 * 1024 / 4 / 256), 256, 0, stream>>>(x, xbf, 8192 * 1024 / 4);
  cvt_f32_bf16<<<dim3(3072 * 1024 / 4 / 256), 256, 0, stream>>>(Wqkv, wqbf, 3072 * 1024 / 4);
  cvt_f32_bf16<<<dim3(1024 * 1024 / 4 / 256), 256, 0, stream>>>(Wout, wobf, 1024 * 1024 / 4);

  bias_fill<<<dim3(64 * 2048 / 256), 256, 0, stream>>>(ts, mk, dec, Bk);

  gemm_bf16<<<dim3(3072 / 128, 8192 / 128), 256, 34816, stream>>>(
      xbf, wqbf, bqkv, 8192, 3072, 1024, 0, Qb, Kb, Vt, nullptr);

  attn_fwd<<<dim3(512), 512, 0, stream>>>(Qb, Kb, Vt, Bk, AO);

  gemm_bf16<<<dim3(1024 / 128, 8192 / 128), 256, 32768, stream>>>(
      AO, wobf, bout, 8192, 1024, 1024, 1, nullptr, nullptr, nullptr, out);
}